// Round 4
// baseline (417.812 us; speedup 1.0000x reference)
//
#include <hip/hip_runtime.h>
#include <hip/hip_bf16.h>

#define N_EDGES 500000
#define N_NODES 50000
#define LN_EPS 1e-5f

typedef __attribute__((ext_vector_type(8))) short bf16x8;
typedef __attribute__((ext_vector_type(4))) short bf16x4;
typedef __attribute__((ext_vector_type(4))) float f32x4;

static __device__ __forceinline__ short f2bf(float f) {
  return __builtin_bit_cast(short, __float2bfloat16(f));
}
static __device__ __forceinline__ float bf2f(short s) {
  unsigned u = ((unsigned)(unsigned short)s) << 16;
  return __builtin_bit_cast(float, u);
}

// w1t [128n][384k], w2t [128n][128k] bf16; optionally nfeat -> nbf bf16.
__global__ void convert_kernel(const float* __restrict__ W1,
                               const float* __restrict__ W2,
                               const float* __restrict__ nfeat,
                               short* __restrict__ w1t, short* __restrict__ w2t,
                               short* __restrict__ nbf, int do_nbf) {
  const int step = gridDim.x * blockDim.x;
  const int t0 = blockIdx.x * blockDim.x + threadIdx.x;
  for (int i = t0; i < 384 * 128; i += step) {
    int n = i / 384, k = i - n * 384;
    w1t[i] = f2bf(W1[k * 128 + n]);
  }
  for (int i = t0; i < 128 * 128; i += step) {
    int n = i >> 7, k = i & 127;
    w2t[i] = f2bf(W2[k * 128 + n]);
  }
  if (do_nbf) {
    for (int i = t0; i < N_NODES * 128 / 4; i += step) {
      f32x4 v = *(const f32x4*)(nfeat + i * 4);
      bf16x4 o;
#pragma unroll
      for (int q = 0; q < 4; ++q) o[q] = f2bf(v[q]);
      *(bf16x4*)(nbf + i * 4) = o;
    }
  }
}

// One block = 4 waves = 128 edges; wave owns 32 rows. All A-fragments
// prefetched upfront (24 loads in flight), pinned by sched_barrier.
// Single barrier (before cooperative flush).
template <bool NBF>
__global__ __launch_bounds__(256, 2) void edge_mlp_kernel(
    const float* __restrict__ efeat, const float* __restrict__ nfeat,
    const short* __restrict__ nbf,
    const int* __restrict__ src, const int* __restrict__ dst,
    const short* __restrict__ w1t, const short* __restrict__ w2t,
    const float* __restrict__ b1, const float* __restrict__ b2,
    const float* __restrict__ gamma, const float* __restrict__ beta,
    float* __restrict__ out) {
  __shared__ short Hlds[128 * 128];  // 32 KB, XOR-swizzled; H tile then out tile
  char* hb = (char*)Hlds;

  const int tid = threadIdx.x;
  const int lane = tid & 63;
  const int wave = tid >> 6;
  const int lrow = lane & 15;   // A row / C col
  const int kgrp = lane >> 4;   // 0..3
  const int rbase = wave * 32;
  const int ebase = blockIdx.x * 128;

  // ---- indices first (longest dependency pole) ----
  int ec[2], is[2], id[2];
#pragma unroll
  for (int m = 0; m < 2; ++m) {
    int e = ebase + rbase + m * 16 + lrow;
    ec[m] = e < N_EDGES ? e : (N_EDGES - 1);
    is[m] = src[ec[m]];
    id[m] = dst[ec[m]];
  }

  // ---- prefetch seg0 (efeat fp32, contiguous rows): 16 loads, 64 regs ----
  f32x4 s0[2][4][2];
#pragma unroll
  for (int m = 0; m < 2; ++m) {
    const float* pe = efeat + (size_t)ec[m] * 128;
#pragma unroll
    for (int ks = 0; ks < 4; ++ks) {
      const float* p = pe + ks * 32 + kgrp * 8;
      s0[m][ks][0] = *(const f32x4*)p;
      s0[m][ks][1] = *(const f32x4*)(p + 4);
    }
  }

  // ---- prefetch seg1/seg2 gathers ----
  bf16x8 ga[2][8];      // NBF path: 16 loads, 64 regs
  f32x4 g32[2][8][2];   // fallback fp32 path (heavier)
  if (NBF) {
#pragma unroll
    for (int m = 0; m < 2; ++m) {
#pragma unroll
      for (int t = 0; t < 8; ++t) {
        int node = (t < 4) ? is[m] : id[m];
        int koff = (t & 3) * 32 + kgrp * 8;
        ga[m][t] = *(const bf16x8*)(nbf + (size_t)node * 128 + koff);
      }
    }
  } else {
#pragma unroll
    for (int m = 0; m < 2; ++m) {
#pragma unroll
      for (int t = 0; t < 8; ++t) {
        int node = (t < 4) ? is[m] : id[m];
        const float* p = nfeat + (size_t)node * 128 + (t & 3) * 32 + kgrp * 8;
        g32[m][t][0] = *(const f32x4*)p;
        g32[m][t][1] = *(const f32x4*)(p + 4);
      }
    }
  }
  __builtin_amdgcn_sched_barrier(0);  // pin: prefetch issues stay above

  f32x4 acc[2][8];
#pragma unroll
  for (int m = 0; m < 2; ++m)
#pragma unroll
    for (int n = 0; n < 8; ++n) acc[m][n] = (f32x4)0.f;

  // ---- GEMM1: K=384, 12 k-steps ----
#pragma unroll
  for (int ks = 0; ks < 12; ++ks) {
    bf16x8 a[2];
#pragma unroll
    for (int m = 0; m < 2; ++m) {
      if (ks < 4) {
        f32x4 lo = s0[m][ks][0], hi = s0[m][ks][1];
        bf16x8 t;
#pragma unroll
        for (int q = 0; q < 4; ++q) { t[q] = f2bf(lo[q]); t[4 + q] = f2bf(hi[q]); }
        a[m] = t;
      } else if (NBF) {
        a[m] = ga[m][ks - 4];
      } else {
        f32x4 lo = g32[m][ks - 4][0], hi = g32[m][ks - 4][1];
        bf16x8 t;
#pragma unroll
        for (int q = 0; q < 4; ++q) { t[q] = f2bf(lo[q]); t[4 + q] = f2bf(hi[q]); }
        a[m] = t;
      }
    }
    const int k0 = ks * 32 + kgrp * 8;
#pragma unroll
    for (int n = 0; n < 8; ++n) {
      bf16x8 b = *(const bf16x8*)(w1t + (n * 16 + lrow) * 384 + k0);
      acc[0][n] = __builtin_amdgcn_mfma_f32_16x16x32_bf16(a[0], b, acc[0][n], 0, 0, 0);
      acc[1][n] = __builtin_amdgcn_mfma_f32_16x16x32_bf16(a[1], b, acc[1][n], 0, 0, 0);
    }
  }

  // ---- bias1 + SiLU -> H (bf16, XOR swizzle). Own rows only: no barrier. ----
  float b1v[8];
#pragma unroll
  for (int n = 0; n < 8; ++n) b1v[n] = b1[n * 16 + lrow];

#pragma unroll
  for (int m = 0; m < 2; ++m)
#pragma unroll
    for (int n = 0; n < 8; ++n)
#pragma unroll
      for (int r = 0; r < 4; ++r) {
        float x = acc[m][n][r] + b1v[n];
        float h = x / (1.f + __expf(-x));
        int row = rbase + m * 16 + kgrp * 4 + r;  // C/D: row=(lane>>4)*4+reg
        int col = n * 16 + lrow;                  // C/D: col=lane&15
        int byte = ((row << 8) + (col << 1)) ^ ((row & 7) << 4);
        *(short*)(hb + byte) = f2bf(h);
      }

  // ---- GEMM2: K=128 (A rows = own rows; intra-wave LDS ordering suffices) ----
  f32x4 acc2[2][8];
#pragma unroll
  for (int m = 0; m < 2; ++m)
#pragma unroll
    for (int n = 0; n < 8; ++n) acc2[m][n] = (f32x4)0.f;

#pragma unroll
  for (int ks = 0; ks < 4; ++ks) {
    bf16x8 a2[2];
#pragma unroll
    for (int m = 0; m < 2; ++m) {
      int row = rbase + m * 16 + lrow;
      int byte = ((row << 8) + ((ks * 32 + kgrp * 8) << 1)) ^ ((row & 7) << 4);
      a2[m] = *(const bf16x8*)(hb + byte);
    }
#pragma unroll
    for (int n = 0; n < 8; ++n) {
      bf16x8 b = *(const bf16x8*)(w2t + (n * 16 + lrow) * 128 + ks * 32 + kgrp * 8);
#pragma unroll
      for (int m = 0; m < 2; ++m)
        acc2[m][n] = __builtin_amdgcn_mfma_f32_16x16x32_bf16(a2[m], b, acc2[m][n], 0, 0, 0);
    }
  }

  // ---- bias2 + LayerNorm -> bf16 out tile (own rows) ----
  float b2v[8], gv[8], bev[8];
#pragma unroll
  for (int n = 0; n < 8; ++n) {
    int c = n * 16 + lrow;
    b2v[n] = b2[c];
    gv[n] = gamma[c];
    bev[n] = beta[c];
  }

#pragma unroll
  for (int m = 0; m < 2; ++m) {
    float s1[4], s2[4];
#pragma unroll
    for (int r = 0; r < 4; ++r) { s1[r] = 0.f; s2[r] = 0.f; }
#pragma unroll
    for (int n = 0; n < 8; ++n)
#pragma unroll
      for (int r = 0; r < 4; ++r) {
        float x = acc2[m][n][r] + b2v[n];
        s1[r] += x;
        s2[r] += x * x;
      }
#pragma unroll
    for (int off = 1; off < 16; off <<= 1)
#pragma unroll
      for (int r = 0; r < 4; ++r) {
        s1[r] += __shfl_xor(s1[r], off, 64);
        s2[r] += __shfl_xor(s2[r], off, 64);
      }
#pragma unroll
    for (int r = 0; r < 4; ++r) {
      float mu = s1[r] * (1.f / 128.f);
      float var = s2[r] * (1.f / 128.f) - mu * mu;
      float rs = rsqrtf(var + LN_EPS);
      int row = rbase + m * 16 + kgrp * 4 + r;
#pragma unroll
      for (int n = 0; n < 8; ++n) {
        float x = acc2[m][n][r] + b2v[n];
        float y = (x - mu) * rs * gv[n] + bev[n];
        int col = n * 16 + lrow;
        int byte = ((row << 8) + (col << 1)) ^ ((row & 7) << 4);
        *(short*)(hb + byte) = f2bf(y);
      }
    }
  }
  __syncthreads();  // out tile complete -> cooperative flush

  // ---- coalesced flush: bf16 tile + efeat fp32 residual -> fp32 out ----
#pragma unroll
  for (int it = 0; it < 8; ++it) {
    int idx = it * 256 + tid;
    int row = idx >> 4;
    int c8 = (idx & 15) * 8;
    int e = ebase + row;
    if (e < N_EDGES) {
      int byte = ((row << 8) + (c8 << 1)) ^ ((row & 7) << 4);
      bf16x8 v = *(const bf16x8*)(hb + byte);
      const float* er = efeat + (size_t)e * 128 + c8;
      float* orow = out + (size_t)e * 128 + c8;
      f32x4 lo = *(const f32x4*)er;
      f32x4 hi = *(const f32x4*)(er + 4);
      f32x4 o0, o1;
#pragma unroll
      for (int q = 0; q < 4; ++q) {
        o0[q] = bf2f(v[q]) + lo[q];
        o1[q] = bf2f(v[4 + q]) + hi[q];
      }
      *(f32x4*)orow = o0;
      *(f32x4*)(orow + 4) = o1;
    }
  }
}

extern "C" void kernel_launch(void* const* d_in, const int* in_sizes, int n_in,
                              void* d_out, int out_size, void* d_ws, size_t ws_size,
                              hipStream_t stream) {
  const float* efeat = (const float*)d_in[0];
  const float* nfeat = (const float*)d_in[1];
  const int* src = (const int*)d_in[2];
  const int* dst = (const int*)d_in[3];
  const float* W1 = (const float*)d_in[4];
  const float* b1 = (const float*)d_in[5];
  const float* W2 = (const float*)d_in[6];
  const float* b2 = (const float*)d_in[7];
  const float* gamma = (const float*)d_in[8];
  const float* beta = (const float*)d_in[9];
  float* out = (float*)d_out;

  short* w1t = (short*)d_ws;               // 96 KB
  short* w2t = w1t + 384 * 128;            // 32 KB
  short* nbf = w2t + 128 * 128;            // 12.8 MB (if it fits)
  const size_t need = (size_t)(384 * 128 + 128 * 128 + N_NODES * 128) * sizeof(short);
  const bool use_nbf = ws_size >= need;

  // nfeat passthrough (second tuple element)
  hipMemcpyAsync(out + (size_t)N_EDGES * 128, nfeat,
                 (size_t)N_NODES * 128 * sizeof(float),
                 hipMemcpyDeviceToDevice, stream);

  convert_kernel<<<2048, 256, 0, stream>>>(W1, W2, nfeat, w1t, w2t,
                                           use_nbf ? nbf : w1t, use_nbf ? 1 : 0);

  const int nblocks = (N_EDGES + 127) / 128;  // 3907
  if (use_nbf)
    edge_mlp_kernel<true><<<nblocks, 256, 0, stream>>>(
        efeat, nfeat, nbf, src, dst, w1t, w2t, b1, b2, gamma, beta, out);
  else
    edge_mlp_kernel<false><<<nblocks, 256, 0, stream>>>(
        efeat, nfeat, nbf, src, dst, w1t, w2t, b1, b2, gamma, beta, out);
}

// Round 5
// 379.095 us; speedup vs baseline: 1.1021x; 1.1021x over previous
//
#include <hip/hip_runtime.h>
#include <hip/hip_bf16.h>

#define N_EDGES 500000
#define N_NODES 50000
#define NT ((N_EDGES + 63) / 64)  // 7813 tiles of 64 edges
#define GRID 512
#define LN_EPS 1e-5f

typedef __attribute__((ext_vector_type(8))) short bf16x8;
typedef __attribute__((ext_vector_type(4))) float f32x4;

static __device__ __forceinline__ short f2bf(float f) {
  return __builtin_bit_cast(short, __float2bfloat16(f));
}
static __device__ __forceinline__ float bf2f(short s) {
  unsigned u = ((unsigned)(unsigned short)s) << 16;
  return __builtin_bit_cast(float, u);
}
static __device__ __forceinline__ void gload16(const void* g, void* l) {
  __builtin_amdgcn_global_load_lds(
      (const __attribute__((address_space(1))) unsigned int*)g,
      (__attribute__((address_space(3))) unsigned int*)l, 16, 0, 0);
}
// lgkm-only barrier: does NOT drain in-flight global_load_lds (vmcnt)
static __device__ __forceinline__ void bar_lds() {
  __builtin_amdgcn_sched_barrier(0);
  asm volatile("s_waitcnt lgkmcnt(0)" ::: "memory");
  __builtin_amdgcn_s_barrier();
  __builtin_amdgcn_sched_barrier(0);
}

// w1t [128n][384k] bf16, w2t [128n][128k] bf16, nbf = bf16(nfeat), + nfeat passthrough
__global__ void convert_kernel(const float* __restrict__ W1,
                               const float* __restrict__ W2,
                               const float* __restrict__ nfeat,
                               short* __restrict__ w1t, short* __restrict__ w2t,
                               short* __restrict__ nbf, float* __restrict__ outn) {
  const int step = gridDim.x * blockDim.x;
  const int t0 = blockIdx.x * blockDim.x + threadIdx.x;
  for (int i = t0; i < 384 * 128; i += step) {
    int n = i / 384, k = i - n * 384;
    w1t[i] = f2bf(W1[k * 128 + n]);
  }
  for (int i = t0; i < 128 * 128; i += step) {
    int n = i >> 7, k = i & 127;
    w2t[i] = f2bf(W2[k * 128 + n]);
  }
  for (int i = t0; i < N_NODES * 128 / 4; i += step) {
    f32x4 v = *(const f32x4*)(nfeat + (size_t)i * 4);
    short o4[4];
#pragma unroll
    for (int q = 0; q < 4; ++q) o4[q] = f2bf(v[q]);
    *(unsigned long long*)(nbf + (size_t)i * 4) = *(unsigned long long*)o4;
    *(f32x4*)(outn + (size_t)i * 4) = v;  // passthrough output 1
  }
}

// Persistent: 512 blocks x 512 threads (8 waves). Tile = 64 edges.
// Wave w owns output cols [16w,16w+16). Weights register-resident.
// cat tile (bf16) in LDS: catA = efeat seg (reg-staged+cvt), catB = src/dst
// gathers via global_load_lds with pre-swizzled per-lane source.
__global__ __launch_bounds__(512, 4) void edge_mlp_persistent(
    const float* __restrict__ efeat, const short* __restrict__ nbf,
    const int* __restrict__ src, const int* __restrict__ dst,
    const short* __restrict__ w1t, const short* __restrict__ w2t,
    const float* __restrict__ b1, const float* __restrict__ b2,
    const float* __restrict__ gamma, const float* __restrict__ beta,
    float* __restrict__ out) {
  __shared__ __align__(16) char smem[70656];
  char* catA = smem;                       // [64 rows][256 B] bf16, swz
  char* catB = smem + 16384;               // [64 rows][512 B] bf16, swz
  char* Hbuf = smem + 49152;               // [64 rows][256 B] bf16, swz (H then outbf)
  float* scr = (float*)(smem + 65536);     // [64][18] f32 (padded stride)
  float* scr2 = (float*)(smem + 70144);    // [64][2] f32 (mu, rs)

  const int tid = threadIdx.x;
  const int lane = tid & 63;
  const int w = tid >> 6;  // wave 0..7
  const int lrow = lane & 15;
  const int kgrp = (lane >> 4) & 3;

  // ---- persistent weights in registers (loaded once per block) ----
  bf16x8 B1[12], B2[4];
#pragma unroll
  for (int ks = 0; ks < 12; ++ks)
    B1[ks] = *(const bf16x8*)(w1t + (w * 16 + lrow) * 384 + ks * 32 + kgrp * 8);
#pragma unroll
  for (int ks = 0; ks < 4; ++ks)
    B2[ks] = *(const bf16x8*)(w2t + (w * 16 + lrow) * 128 + ks * 32 + kgrp * 8);
  const int col = w * 16 + lrow;
  const float b1v = b1[col], b2v = b2[col], gv = gamma[col], bev = beta[col];

  // ---- per-lane gather statics: 4 global_load_lds instrs per wave ----
  int grow[4], gkb[4], gs[4];
#pragma unroll
  for (int i = 0; i < 4; ++i) {
    int F = w * 4096 + i * 1024 + lane * 16;     // flat catB byte offset
    grow[i] = F >> 9;                            // row 0..63
    int win = (F & 511) ^ ((grow[i] & 7) << 4);  // pre-swizzle (involution)
    gs[i] = win < 256;                           // seg1 (src) vs seg2 (dst)
    gkb[i] = win & 255;                          // byte within node row
  }

  // flush/stage mapping: thread -> (row, 16-col chunk); same map for stage & flush
  const int frow = tid >> 3;
  const int fc = (tid & 7) * 16;

  f32x4 S[4];  // staged efeat fp32 (64 B)
  auto stage_S = [&](int t) {
    int e = t * 64 + frow;
    e = e < N_EDGES ? e : (N_EDGES - 1);
    const float* p = efeat + (size_t)e * 128 + fc;
#pragma unroll
    for (int q = 0; q < 4; ++q) S[q] = *(const f32x4*)(p + q * 4);
  };
  auto write_catA = [&]() {
    bf16x8 v0, v1;
#pragma unroll
    for (int j = 0; j < 4; ++j) {
      v0[j] = f2bf(S[0][j]); v0[4 + j] = f2bf(S[1][j]);
      v1[j] = f2bf(S[2][j]); v1[4 + j] = f2bf(S[3][j]);
    }
    int base = frow * 256, swz = (frow & 7) << 4, b0 = fc * 2;
    *(bf16x8*)(catA + base + (b0 ^ swz)) = v0;
    *(bf16x8*)(catA + base + ((b0 + 16) ^ swz)) = v1;
  };
  auto issue_gathers = [&](int t) {
#pragma unroll
    for (int i = 0; i < 4; ++i) {
      int e = t * 64 + grow[i];
      e = e < N_EDGES ? e : (N_EDGES - 1);
      int node = gs[i] ? src[e] : dst[e];
      gload16((const char*)nbf + (size_t)node * 256 + gkb[i],
              catB + w * 4096 + i * 1024);
    }
  };

  // ---- prologue: stage tile t0 ----
  const int t0 = blockIdx.x;
  stage_S(t0);
  write_catA();
  issue_gathers(t0);

  for (int t = t0; t < NT; t += GRID) {
    const int tn = t + GRID;  // next tile (clamped inside helpers)
    __syncthreads();  // full barrier: drains vmcnt -> catA/catB(t) ready

    // ---- GEMM1: K=384 (catA k<128, catB k>=128), B in registers ----
    f32x4 acc[4];
#pragma unroll
    for (int m = 0; m < 4; ++m) acc[m] = (f32x4)0.f;
#pragma unroll
    for (int ks = 0; ks < 12; ++ks) {
      const int kb = (ks < 4) ? (ks * 64 + kgrp * 16) : ((ks - 4) * 64 + kgrp * 16);
      bf16x8 a[4];
#pragma unroll
      for (int m = 0; m < 4; ++m) {
        int row = m * 16 + lrow;
        char* base = (ks < 4) ? (catA + row * 256) : (catB + row * 512);
        a[m] = *(const bf16x8*)(base + (kb ^ ((row & 7) << 4)));
      }
#pragma unroll
      for (int m = 0; m < 4; ++m)
        acc[m] = __builtin_amdgcn_mfma_f32_16x16x32_bf16(a[m], B1[ks], acc[m], 0, 0, 0);
    }

    // ---- SiLU -> H (bf16, swz) ----
#pragma unroll
    for (int m = 0; m < 4; ++m)
#pragma unroll
      for (int r = 0; r < 4; ++r) {
        float x = acc[m][r] + b1v;
        float h = x / (1.f + __expf(-x));
        int row = m * 16 + kgrp * 4 + r;
        *(short*)(Hbuf + row * 256 + ((col * 2) ^ ((row & 7) << 4))) = f2bf(h);
      }
    bar_lds();  // H done; cat(t) consumed by GEMM1

    // ---- prefetch next tile: efeat regs + async LDS gathers ----
    stage_S(tn);
    issue_gathers(tn);

    // ---- GEMM2: K=128 from H ----
    f32x4 acc2[4];
#pragma unroll
    for (int m = 0; m < 4; ++m) acc2[m] = (f32x4)0.f;
#pragma unroll
    for (int ks = 0; ks < 4; ++ks) {
      bf16x8 a[4];
#pragma unroll
      for (int m = 0; m < 4; ++m) {
        int row = m * 16 + lrow;
        a[m] = *(const bf16x8*)(Hbuf + row * 256 +
                                ((ks * 64 + kgrp * 16) ^ ((row & 7) << 4)));
      }
#pragma unroll
      for (int m = 0; m < 4; ++m)
        acc2[m] = __builtin_amdgcn_mfma_f32_16x16x32_bf16(a[m], B2[ks], acc2[m], 0, 0, 0);
    }

    // ---- LN partials: reduce 16 cols within wave, stash per-wave sums ----
#pragma unroll
    for (int m = 0; m < 4; ++m)
#pragma unroll
      for (int r = 0; r < 4; ++r) {
        float x = acc2[m][r] + b2v;
        float p1 = x, p2 = x * x;
#pragma unroll
        for (int off = 1; off < 16; off <<= 1) {
          p1 += __shfl_xor(p1, off, 64);
          p2 += __shfl_xor(p2, off, 64);
        }
        if (lrow == 0) {
          int row = m * 16 + kgrp * 4 + r;
          scr[row * 18 + w * 2] = p1;
          scr[row * 18 + w * 2 + 1] = p2;
        }
      }
    bar_lds();  // partials ready (also: all GEMM2 H-reads complete)

    if (tid < 64) {
      float s1 = 0.f, s2 = 0.f;
#pragma unroll
      for (int i = 0; i < 8; ++i) {
        s1 += scr[tid * 18 + i * 2];
        s2 += scr[tid * 18 + i * 2 + 1];
      }
      float mu = s1 * (1.f / 128.f);
      float var = s2 * (1.f / 128.f) - mu * mu;
      scr2[tid * 2] = mu;
      scr2[tid * 2 + 1] = rsqrtf(var + LN_EPS);
    }
    bar_lds();  // stats ready

    // ---- normalize -> outbf (reuse Hbuf region) ----
#pragma unroll
    for (int m = 0; m < 4; ++m)
#pragma unroll
      for (int r = 0; r < 4; ++r) {
        int row = m * 16 + kgrp * 4 + r;
        float mu = scr2[row * 2], rs = scr2[row * 2 + 1];
        float x = acc2[m][r] + b2v;
        float y = (x - mu) * rs * gv + bev;
        *(short*)(Hbuf + row * 256 + ((col * 2) ^ ((row & 7) << 4))) = f2bf(y);
      }
    bar_lds();  // outbf ready

    // ---- flush: outbf + residual (bf16 from catA, same-thread rows) ----
    {
      int e = t * 64 + frow;
      int base = frow * 256, swz = (frow & 7) << 4, b0 = fc * 2;
      bf16x8 o0 = *(const bf16x8*)(Hbuf + base + (b0 ^ swz));
      bf16x8 o1 = *(const bf16x8*)(Hbuf + base + ((b0 + 16) ^ swz));
      bf16x8 r0 = *(const bf16x8*)(catA + base + (b0 ^ swz));
      bf16x8 r1 = *(const bf16x8*)(catA + base + ((b0 + 16) ^ swz));
      if (e < N_EDGES) {
        float* op = out + (size_t)e * 128 + fc;
        f32x4 v;
#pragma unroll
        for (int q = 0; q < 4; ++q) v[q] = bf2f(o0[q]) + bf2f(r0[q]);
        *(f32x4*)op = v;
#pragma unroll
        for (int q = 0; q < 4; ++q) v[q] = bf2f(o0[4 + q]) + bf2f(r0[4 + q]);
        *(f32x4*)(op + 4) = v;
#pragma unroll
        for (int q = 0; q < 4; ++q) v[q] = bf2f(o1[q]) + bf2f(r1[q]);
        *(f32x4*)(op + 8) = v;
#pragma unroll
        for (int q = 0; q < 4; ++q) v[q] = bf2f(o1[4 + q]) + bf2f(r1[4 + q]);
        *(f32x4*)(op + 12) = v;
      }
    }
    // ---- overwrite own catA row-chunk for next tile (same-thread: no race) ----
    write_catA();
  }
}

// ---- never-taken-in-practice fallback (tiny ws): block-per-edge, fp32 ----
__global__ void edge_simple(const float* __restrict__ efeat, const float* __restrict__ nfeat,
                            const int* __restrict__ src, const int* __restrict__ dst,
                            const float* __restrict__ W1, const float* __restrict__ b1,
                            const float* __restrict__ W2, const float* __restrict__ b2,
                            const float* __restrict__ g, const float* __restrict__ be,
                            float* __restrict__ out) {
  int e = blockIdx.x, j = threadIdx.x;
  __shared__ float cat[384], h[128], red[128];
  cat[j] = efeat[(size_t)e * 128 + j];
  cat[128 + j] = nfeat[(size_t)src[e] * 128 + j];
  cat[256 + j] = nfeat[(size_t)dst[e] * 128 + j];
  __syncthreads();
  float s = b1[j];
  for (int k = 0; k < 384; ++k) s += cat[k] * W1[k * 128 + j];
  h[j] = s / (1.f + expf(-s));
  __syncthreads();
  float o = b2[j];
  for (int k = 0; k < 128; ++k) o += h[k] * W2[k * 128 + j];
  red[j] = o;
  __syncthreads();
  __shared__ float mu, rs;
  if (j == 0) {
    float s1 = 0, s2 = 0;
    for (int k = 0; k < 128; ++k) { s1 += red[k]; s2 += red[k] * red[k]; }
    mu = s1 / 128.f;
    rs = rsqrtf(s2 / 128.f - mu * mu + LN_EPS);
  }
  __syncthreads();
  out[(size_t)e * 128 + j] = (o - mu) * rs * g[j] + be[j] + efeat[(size_t)e * 128 + j];
}

extern "C" void kernel_launch(void* const* d_in, const int* in_sizes, int n_in,
                              void* d_out, int out_size, void* d_ws, size_t ws_size,
                              hipStream_t stream) {
  const float* efeat = (const float*)d_in[0];
  const float* nfeat = (const float*)d_in[1];
  const int* src = (const int*)d_in[2];
  const int* dst = (const int*)d_in[3];
  const float* W1 = (const float*)d_in[4];
  const float* b1 = (const float*)d_in[5];
  const float* W2 = (const float*)d_in[6];
  const float* b2 = (const float*)d_in[7];
  const float* gamma = (const float*)d_in[8];
  const float* beta = (const float*)d_in[9];
  float* out = (float*)d_out;

  short* w1t = (short*)d_ws;         // 96 KB
  short* w2t = w1t + 384 * 128;      // 32 KB
  short* nbf = w2t + 128 * 128;      // 12.8 MB
  const size_t need =
      (size_t)(384 * 128 + 128 * 128 + (size_t)N_NODES * 128) * sizeof(short);

  if (ws_size >= need) {
    convert_kernel<<<1024, 256, 0, stream>>>(W1, W2, nfeat, w1t, w2t, nbf,
                                             out + (size_t)N_EDGES * 128);
    edge_mlp_persistent<<<GRID, 512, 0, stream>>>(efeat, nbf, src, dst, w1t, w2t,
                                                  b1, b2, gamma, beta, out);
  } else {
    hipMemcpyAsync(out + (size_t)N_EDGES * 128, nfeat,
                   (size_t)N_NODES * 128 * sizeof(float),
                   hipMemcpyDeviceToDevice, stream);
    edge_simple<<<N_EDGES, 128, 0, stream>>>(efeat, nfeat, src, dst, W1, b1, W2,
                                             b2, gamma, beta, out);
  }
}